// Round 7
// baseline (230.380 us; speedup 1.0000x reference)
//
#include <hip/hip_runtime.h>

// KeyValueMemoryNetwork: B=16, S=2048, C=16, D=256, V=100000
// R7 = R6 with compile fix: nontemporal builtins need clang native vector
// types, not HIP_vector_type. Structure: register gather + online softmax
// over 2x8 rows; nontemporal hidden-read / out-write so L2/L3 retain the
// 102 MB table (FETCH=270MB vs 136MB compulsory => stream pollution theory).

#define KV_C 16
#define KV_D 256
#define KV_CHUNK 8
#define KV_TOKENS (16 * 2048)

typedef float f32x4 __attribute__((ext_vector_type(4)));

__global__ __launch_bounds__(256, 4) void kv_mem_kernel(
    const int* __restrict__ seq,      // [TOKENS, C] int32
    const float* __restrict__ hidden, // [TOKENS, D]
    const float* __restrict__ table,  // [V, D]
    float* __restrict__ out)          // [TOKENS, D]
{
    const int wave = threadIdx.x >> 6;
    const int lane = threadIdx.x & 63;
    const int token = blockIdx.x * 4 + wave;

    // hidden chunk for this lane — nontemporal: streamed once, don't cache
    const f32x4 h = __builtin_nontemporal_load(
        (const f32x4*)(hidden + (size_t)token * KV_D + lane * 4));

    // lanes 0..15 hold the 16 indices; broadcast via shuffle
    const int* sp = seq + (size_t)token * KV_C;
    int myidx = (lane < KV_C) ? sp[lane] : 0;
    const unsigned long long nz = __ballot(myidx != 0);

    // online-softmax state (wave-uniform after each chunk's reduce)
    float m_run = 0.0f;   // safe stand-in for -inf: l_run==0 and o==0
    float l_run = 0.0f;
    f32x4 o = (f32x4){0.f, 0.f, 0.f, 0.f};

    #pragma unroll
    for (int ch = 0; ch < KV_C / KV_CHUNK; ++ch) {
        const int cbase = ch * KV_CHUNK;

        // Phase A: 8 unconditional gathers (row 0 is valid memory; padding
        // handled by mask). These stay CACHED — the table is the reuse set.
        f32x4 e[KV_CHUNK];
        #pragma unroll
        for (int j = 0; j < KV_CHUNK; ++j) {
            const int idx = __shfl(myidx, cbase + j);   // wave-uniform
            e[j] = *(const f32x4*)(table + (size_t)idx * KV_D + lane * 4);
        }

        // Phase B: masked partial dots (padded slots -> u == 0 exactly,
        // matching the reference, which softmaxes over zero rows too).
        float u[KV_CHUNK];
        #pragma unroll
        for (int j = 0; j < KV_CHUNK; ++j) {
            const float msk = ((nz >> (cbase + j)) & 1ULL) ? 1.0f : 0.0f;
            u[j] = msk * (h.x * e[j].x + h.y * e[j].y +
                          h.z * e[j].z + h.w * e[j].w);
        }

        // butterfly reduce the 8 scores across the 64-lane wave
        #pragma unroll
        for (int s = 32; s >= 1; s >>= 1) {
            #pragma unroll
            for (int j = 0; j < KV_CHUNK; ++j) {
                u[j] += __shfl_xor(u[j], s);
            }
        }

        // Phase C: online-softmax update + combine while rows are live.
        float m_new = m_run;
        #pragma unroll
        for (int j = 0; j < KV_CHUNK; ++j) m_new = fmaxf(m_new, u[j]);
        const float scale = __expf(m_run - m_new);
        l_run *= scale;
        o *= scale;
        #pragma unroll
        for (int j = 0; j < KV_CHUNK; ++j) {
            const float w = __expf(u[j] - m_new);
            l_run += w;                                   // Z includes padded slots
            const float msk = ((nz >> (cbase + j)) & 1ULL) ? 1.0f : 0.0f;
            const float wm = w * msk;                     // zero vector into o
            o.x += wm * e[j].x;
            o.y += wm * e[j].y;
            o.z += wm * e[j].z;
            o.w += wm * e[j].w;
        }
        m_run = m_new;
    }

    const float inv = 1.0f / l_run;
    o *= inv;

    // out is write-once — nontemporal store, don't evict table from L2/L3
    __builtin_nontemporal_store(o,
        (f32x4*)(out + (size_t)token * KV_D + lane * 4));
}

extern "C" void kernel_launch(void* const* d_in, const int* in_sizes, int n_in,
                              void* d_out, int out_size, void* d_ws, size_t ws_size,
                              hipStream_t stream) {
    const int*   seq    = (const int*)d_in[0];
    const float* hidden = (const float*)d_in[1];
    const float* table  = (const float*)d_in[2];
    float*       out    = (float*)d_out;

    dim3 grid(KV_TOKENS / 4);   // 8192 blocks, 4 waves (tokens) per block
    dim3 block(256);
    kv_mem_kernel<<<grid, block, 0, stream>>>(seq, hidden, table, out);
}